// Round 11
// baseline (402.832 us; speedup 1.0000x reference)
//
#include <hip/hip_runtime.h>
#include <stdint.h>

typedef unsigned short u16;
typedef __attribute__((ext_vector_type(8))) short short8;
typedef __attribute__((ext_vector_type(4))) float floatx4;

#define DEV __device__ __forceinline__

DEV u16 f2bf(float f) {  // RNE
  union { float f; unsigned u; } x; x.f = f;
  unsigned u = x.u + 0x7fffu + ((x.u >> 16) & 1u);
  return (u16)(u >> 16);
}
DEV float scrub(float x) {
  return fminf(fmaxf(x, -65504.0f), 65504.0f);
}
DEV void async16(const void* g, void* l) {
  auto gp = reinterpret_cast<const __attribute__((address_space(1))) unsigned int*>(
      reinterpret_cast<uintptr_t>(g));
  auto lp = reinterpret_cast<__attribute__((address_space(3))) unsigned int*>(
      reinterpret_cast<uintptr_t>(l));
  __builtin_amdgcn_global_load_lds(gp, lp, 16, 0, 0);
}
DEV unsigned asu(float f) { union { float f; unsigned u; } x; x.f = f; return x.u; }
DEV float asf(unsigned u) { union { unsigned u; float f; } x; x.u = u; return x.f; }
// RNE f32x2 -> packed bf16x2 (identical rounding to f2bf for normals/zeros)
DEV unsigned cvtpk(float lo, float hi) {
  unsigned r;
  asm("v_cvt_pk_bf16_f32 %0, %1, %2" : "=v"(r) : "v"(lo), "v"(hi));
  return r;
}

// ===========================================================================
// fp32 -> bf16 convert for Wo ONLY (activations + other weights are now
// converted inside proj3's staging). 1M elems, 1024 blocks.
// ===========================================================================
__global__ void cvt1(const float* __restrict__ s, u16* __restrict__ d) {
  int i = blockIdx.x * 256 + threadIdx.x;
  float4 v = ((const float4*)s)[i];
  union { u16 h[4]; uint2 u; } o;
  o.h[0] = f2bf(v.x); o.h[1] = f2bf(v.y); o.h[2] = f2bf(v.z); o.h[3] = f2bf(v.w);
  ((uint2*)d)[i] = o.u;
}

// ===========================================================================
// Projection GEMM — v4: FUSED fp32->bf16 conversion in staging (deletes the
// separate cvt pass over 165 MB). Reg-staging: 2x global_load_dwordx4 per
// 16B bf16 chunk -> v_cvt_pk_bf16_f32 (RNE) -> ds_write_b128 to the SAME
// swizzled LDS layout as before (write-swz == read-swz, rule #21).
// Compute section unchanged. 128x128 tile, BK=64, 3 blocks/CU (VGPR cap).
// z=0 (Q): C^T orient, out head-split (B,H,L,DK), prescaled SCALE*log2e.
// z=1 (K): C^T orient, head-split.
// z=2 (V): C orient, out transposed head-split (B,H,DK,L).
// XCD-aware block swizzle for X-panel L2 reuse.
// ===========================================================================
__global__ __launch_bounds__(256, 3) void proj3(
    const float* __restrict__ Xq, const float* __restrict__ Xk, const float* __restrict__ Xv,
    const float* __restrict__ Wq, const float* __restrict__ Wk, const float* __restrict__ Wv,
    u16* __restrict__ Oq, u16* __restrict__ Ok, u16* __restrict__ Ov)
{
  constexpr int K = 1024;
  constexpr float SC2 = 0.125f * 1.44269504088896f;
  // grid (8,64,3), nwg=1536 (%8==0): bijective XCD swizzle
  int flat = blockIdx.x + 8 * (blockIdx.y + 64 * blockIdx.z);
  int swz = (flat & 7) * 192 + (flat >> 3);
  const int bx = swz & 7, by = (swz >> 3) & 63, z = swz >> 9;

  const float* X = z == 0 ? Xq : (z == 1 ? Xk : Xv);
  const float* W = z == 0 ? Wq : (z == 1 ? Wk : Wv);
  u16* Out = z == 0 ? Oq : (z == 1 ? Ok : Ov);

  const float* A = (z < 2) ? W : X;
  const float* Bp = (z < 2) ? X : W;
  const int m0 = (z < 2) ? bx * 128 : by * 128;
  const int n0 = (z < 2) ? by * 128 : bx * 128;

  const int tid = threadIdx.x;
  const int w = tid >> 6, lane = tid & 63;
  const int quad = lane >> 4, l16 = lane & 15;
  const int wm = (w & 1) * 64, wn = (w >> 1) * 64;

  __shared__ u16 As[128 * 64];
  __shared__ u16 Bs[128 * 64];

  // per-thread staging geometry (constant across k-steps)
  const int rS = tid >> 3, spS = tid & 7;
  const int sS = spS ^ (rS & 7);

  // stage 4 chunks (128 rows) from fp32 src into LDS bf16 tile
  auto stageF = [&](const float* src, int row0, u16* dst, int k0) {
#pragma unroll
    for (int i = 0; i < 4; ++i) {
      int lin = i * 256 + tid;                       // r = rS + i*32
      const float* g = src + (size_t)(row0 + rS + i * 32) * K + k0 + sS * 8;
      float4 u0 = *(const float4*)g;
      float4 u1 = *(const float4*)(g + 4);
      union { unsigned u[4]; uint4 q; } pk;
      pk.u[0] = cvtpk(u0.x, u0.y);
      pk.u[1] = cvtpk(u0.z, u0.w);
      pk.u[2] = cvtpk(u1.x, u1.y);
      pk.u[3] = cvtpk(u1.z, u1.w);
      *(uint4*)&dst[lin * 8] = pk.q;                 // ds_write_b128
    }
  };

  floatx4 acc[4][4];
#pragma unroll
  for (int i = 0; i < 4; ++i)
#pragma unroll
    for (int j = 0; j < 4; ++j) acc[i][j] = (floatx4)0.0f;

  for (int k0 = 0; k0 < K; k0 += 64) {
    stageF(A, m0, As, k0);
    stageF(Bp, n0, Bs, k0);
    __syncthreads();

#pragma unroll
    for (int kk = 0; kk < 2; ++kk) {
      short8 af[4], bf[4];
#pragma unroll
      for (int mi = 0; mi < 4; ++mi) {
        int r = wm + mi * 16 + l16;
        af[mi] = *(const short8*)&As[r * 64 + (((kk * 4 + quad) ^ (r & 7)) * 8)];
      }
#pragma unroll
      for (int ni = 0; ni < 4; ++ni) {
        int r = wn + ni * 16 + l16;
        bf[ni] = *(const short8*)&Bs[r * 64 + (((kk * 4 + quad) ^ (r & 7)) * 8)];
      }
#pragma unroll
      for (int mi = 0; mi < 4; ++mi)
#pragma unroll
        for (int ni = 0; ni < 4; ++ni)
          acc[mi][ni] = __builtin_amdgcn_mfma_f32_16x16x32_bf16(af[mi], bf[ni], acc[mi][ni], 0, 0, 0);
    }
    __syncthreads();
  }

  const float sc = (z == 0) ? SC2 : 1.0f;
#pragma unroll
  for (int mi = 0; mi < 4; ++mi) {
#pragma unroll
    for (int ni = 0; ni < 4; ++ni) {
      int rr = m0 + wm + mi * 16 + quad * 4;
      int cc = n0 + wn + ni * 16 + l16;
      u16 h0 = f2bf(sc * acc[mi][ni][0]);
      u16 h1 = f2bf(sc * acc[mi][ni][1]);
      u16 h2 = f2bf(sc * acc[mi][ni][2]);
      u16 h3 = f2bf(sc * acc[mi][ni][3]);
      uint2 dw; dw.x = h0 | ((unsigned)h1 << 16); dw.y = h2 | ((unsigned)h3 << 16);
      if (z < 2) {
        int bb = cc >> 11, ll = cc & 2047;
        int hh = rr >> 6, dk0 = rr & 63;
        *(uint2*)&Out[(((size_t)bb * 16 + hh) * 2048 + ll) * 64 + dk0] = dw;
      } else {
        int bb = rr >> 11, ll0 = rr & 2047;
        int hh = cc >> 6, dk = cc & 63;
        *(uint2*)&Out[(((size_t)bb * 16 + hh) * 64 + dk) * 2048 + ll0] = dw;
      }
    }
  }
}

// ===========================================================================
// Output GEMM (R9 version, measured best): C = A*Wo^T, 128x128, dbuf 64KB,
// 2 blocks/CU, XCD swizzle. A bf16 head-split, Wo bf16, C fp32 row-major.
// ===========================================================================
__global__ __launch_bounds__(256, 2) void gemm_out(
    const u16* __restrict__ Ah, const u16* __restrict__ Wo, float* __restrict__ Out)
{
  constexpr int K = 1024;
  const int tid = threadIdx.x;
  const int w = tid >> 6, lane = tid & 63;
  const int quad = lane >> 4, l16 = lane & 15;
  // grid (8,64), nwg=512 (%8==0): bijective XCD swizzle
  int flat = blockIdx.x + 8 * blockIdx.y;
  int swz = (flat & 7) * 64 + (flat >> 3);
  const int bx = swz & 7, by = swz >> 3;
  const int m0 = by * 128, n0 = bx * 128;
  const int wm = (w & 1) * 64, wn = (w >> 1) * 64;

  __shared__ u16 SM[32768];

  auto stage = [&](int p, int k0) {
#pragma unroll
    for (int i = 0; i < 4; ++i) {
      int lin = i * 256 + tid;
      int r = lin >> 3, sp = lin & 7, s = sp ^ (r & 7);
      int row = m0 + r;  // head-split A: k-tile == head
      const u16* ga = Ah + (((size_t)(row >> 11) * 16 + (k0 >> 6)) * 2048 + (row & 2047)) * 64 + s * 8;
      async16(ga, &SM[p * 8192 + lin * 8]);
    }
#pragma unroll
    for (int i = 0; i < 4; ++i) {
      int lin = i * 256 + tid;
      int r = lin >> 3, sp = lin & 7, s = sp ^ (r & 7);
      async16(Wo + (size_t)(n0 + r) * K + k0 + s * 8, &SM[16384 + p * 8192 + lin * 8]);
    }
  };

  floatx4 acc[4][4];
#pragma unroll
  for (int i = 0; i < 4; ++i)
#pragma unroll
    for (int j = 0; j < 4; ++j) acc[i][j] = (floatx4)0.0f;

  stage(0, 0);
  asm volatile("s_waitcnt vmcnt(0)" ::: "memory");
  __syncthreads();

  for (int k0 = 0; k0 < K; k0 += 64) {
    const int p = (k0 >> 6) & 1;
    if (k0 + 64 < K) stage(p ^ 1, k0 + 64);
    const u16* Asp = &SM[p * 8192];
    const u16* Bsp = &SM[16384 + p * 8192];

    __builtin_amdgcn_s_setprio(1);
#pragma unroll
    for (int kk = 0; kk < 2; ++kk) {
      short8 af[4], bf[4];
#pragma unroll
      for (int mi = 0; mi < 4; ++mi) {
        int r = wm + mi * 16 + l16;
        af[mi] = *(const short8*)&Asp[r * 64 + (((kk * 4 + quad) ^ (r & 7)) * 8)];
      }
#pragma unroll
      for (int ni = 0; ni < 4; ++ni) {
        int r = wn + ni * 16 + l16;
        bf[ni] = *(const short8*)&Bsp[r * 64 + (((kk * 4 + quad) ^ (r & 7)) * 8)];
      }
#pragma unroll
      for (int mi = 0; mi < 4; ++mi)
#pragma unroll
        for (int ni = 0; ni < 4; ++ni)
          acc[mi][ni] = __builtin_amdgcn_mfma_f32_16x16x32_bf16(af[mi], bf[ni], acc[mi][ni], 0, 0, 0);
    }
    __builtin_amdgcn_s_setprio(0);

    asm volatile("s_waitcnt vmcnt(0)" ::: "memory");
    __syncthreads();
  }

#pragma unroll
  for (int mi = 0; mi < 4; ++mi)
#pragma unroll
    for (int ni = 0; ni < 4; ++ni) {
      int rr = m0 + wm + mi * 16 + quad * 4;
      int cc = n0 + wn + ni * 16 + l16;
#pragma unroll
      for (int reg = 0; reg < 4; ++reg)
        Out[(size_t)(rr + reg) * 1024 + cc] = scrub(acc[mi][ni][reg]);
    }
}

// ===========================================================================
// Flash attention v8 (unchanged): full-tile S cluster, fixed-shift softmax,
// l via ones-MFMA, v_perm bf16 pack, XCD swizzle, Q-overlay 32KB LDS.
// ===========================================================================
__global__ __launch_bounds__(256, 4) void attn3(
    const u16* Qh, const u16* __restrict__ Kh,
    const u16* __restrict__ VT, u16* O)
{
  constexpr int L = 2048, DK = 64, H = 16;
  const int tid = threadIdx.x;
  const int w = tid >> 6, lane = tid & 63;
  const int quad = lane >> 4, l16 = lane & 15;
  // nwg = 16*16*4 = 1024 (%8==0): bijective XCD swizzle.
  int flat = blockIdx.x + 16 * (blockIdx.y + 16 * blockIdx.z);
  int swz = (flat & 7) * 128 + (flat >> 3);
  const int q0 = (swz & 15) * 128;
  const int bh = swz >> 4;          // = b*H + h

  __shared__ u16 SM[4 * 64 * 64];
  u16* const QP = &SM[8192];
  char* const SMb = (char*)&SM[0];

  const u16* Qg = Qh + ((size_t)bh * L + q0) * DK;
  const u16* Kb = Kh + (size_t)bh * L * DK;
  const u16* Vb = VT + (size_t)bh * DK * L;  // rows = dk, length L

#pragma unroll
  for (int i = 0; i < 4; ++i) {
    int lin = i * 256 + tid;
    int r = lin >> 3, sp = lin & 7, s = sp ^ (r & 7);
    async16(Qg + (size_t)r * DK + s * 8, &QP[lin * 8]);
  }

  const int rA = tid >> 3;
  const int sA = (tid & 7) ^ (rA & 7);
  const u16* kg0 = Kb + (size_t)rA * DK + sA * 8;
  const u16* kg1 = kg0 + 32 * DK;                 // rows 32..63
  const u16* vg0 = Vb + (size_t)rA * L + sA * 8;
  const u16* vg1 = vg0 + (size_t)32 * L;
  u16* const ldsB0 = &SM[tid * 8];
  u16* const ldsB1 = &SM[8192 + tid * 8];

  async16(kg0, ldsB0);
  async16(kg1, ldsB0 + 2048);
  async16(vg0, ldsB0 + 4096);
  async16(vg1, ldsB0 + 6144);
  kg0 += 64 * DK; kg1 += 64 * DK; vg0 += 64; vg1 += 64;

  asm volatile("s_waitcnt vmcnt(0)" ::: "memory");
  __syncthreads();

  short8 qf[2][2];
#pragma unroll
  for (int mi = 0; mi < 2; ++mi)
#pragma unroll
    for (int kk = 0; kk < 2; ++kk) {
      int r = w * 32 + mi * 16 + l16;
      qf[mi][kk] = *(const short8*)&QP[r * 64 + (((kk * 4 + quad) ^ (r & 7)) * 8)];
    }
  asm volatile("s_waitcnt lgkmcnt(0)" ::: "memory");
  __syncthreads();

  const int l7 = l16 & 7, qh2 = quad >> 1, qo = (quad & 1) * 8;
  int ka[2], vo[4];
#pragma unroll
  for (int kk = 0; kk < 2; ++kk)
    ka[kk] = l16 * 128 + (((kk * 4 + quad) ^ l7) * 16);
#pragma unroll
  for (int j = 0; j < 4; ++j)
    vo[j] = l16 * 128 + (((qh2 + 2 * j) ^ l7) * 16) + qo;

  short8 onesv;
#pragma unroll
  for (int j = 0; j < 8; ++j) onesv[j] = (short)0x3F80;  // bf16 1.0

  floatx4 oT[4][2];   // [dk-tile][q-tile]
  floatx4 lacc[2];
#pragma unroll
  for (int nd = 0; nd < 4; ++nd)
#pragma unroll
    for (int mi = 0; mi < 2; ++mi) oT[nd][mi] = (floatx4)0.0f;
  lacc[0] = (floatx4)0.0f;
  lacc[1] = (floatx4)0.0f;

  auto body = [&](int PB, u16* ldsN, bool more) {
    if (more) {
      async16(kg0, ldsN);
      async16(kg1, ldsN + 2048);
      async16(vg0, ldsN + 4096);
      async16(vg1, ldsN + 6144);
      kg0 += 64 * DK; kg1 += 64 * DK; vg0 += 64; vg1 += 64;
    }

    floatx4 sT[4][2];
#pragma unroll
    for (int t = 0; t < 4; ++t)
#pragma unroll
      for (int mi = 0; mi < 2; ++mi) sT[t][mi] = (floatx4)0.0f;
    __builtin_amdgcn_s_setprio(1);
#pragma unroll
    for (int kk = 0; kk < 2; ++kk)
#pragma unroll
      for (int t = 0; t < 4; ++t) {
        short8 kf = *(const short8*)(SMb + PB + t * 2048 + ka[kk]);
#pragma unroll
        for (int mi = 0; mi < 2; ++mi)
          sT[t][mi] = __builtin_amdgcn_mfma_f32_16x16x32_bf16(kf, qf[mi][kk], sT[t][mi], 0, 0, 0);
      }
    __builtin_amdgcn_s_setprio(0);

#pragma unroll
    for (int t = 0; t < 4; ++t)
#pragma unroll
      for (int mi = 0; mi < 2; ++mi)
#pragma unroll
        for (int r = 0; r < 4; ++r) sT[t][mi][r] = __builtin_amdgcn_exp2f(sT[t][mi][r]);

    short8 pf[2][2];   // [g][mi]
#pragma unroll
    for (int g = 0; g < 2; ++g)
#pragma unroll
      for (int mi = 0; mi < 2; ++mi) {
        union { unsigned u[4]; short8 v; } up;
        up.u[0] = __builtin_amdgcn_perm(asu(sT[2 * g][mi][1]), asu(sT[2 * g][mi][0]), 0x07060302u);
        up.u[1] = __builtin_amdgcn_perm(asu(sT[2 * g][mi][3]), asu(sT[2 * g][mi][2]), 0x07060302u);
        up.u[2] = __builtin_amdgcn_perm(asu(sT[2 * g + 1][mi][1]), asu(sT[2 * g + 1][mi][0]), 0x07060302u);
        up.u[3] = __builtin_amdgcn_perm(asu(sT[2 * g + 1][mi][3]), asu(sT[2 * g + 1][mi][2]), 0x07060302u);
        pf[g][mi] = up.v;
      }

    __builtin_amdgcn_s_setprio(1);
#pragma unroll
    for (int g = 0; g < 2; ++g) {
#pragma unroll
      for (int nd = 0; nd < 4; ++nd) {
        union { uint2 ab[2]; short8 v; } uv;
        uv.ab[0] = *(const uint2*)(SMb + PB + 8192 + nd * 2048 + vo[2 * g]);
        uv.ab[1] = *(const uint2*)(SMb + PB + 8192 + nd * 2048 + vo[2 * g + 1]);
#pragma unroll
        for (int mi = 0; mi < 2; ++mi)
          oT[nd][mi] = __builtin_amdgcn_mfma_f32_16x16x32_bf16(uv.v, pf[g][mi], oT[nd][mi], 0, 0, 0);
      }
#pragma unroll
      for (int mi = 0; mi < 2; ++mi)
        lacc[mi] = __builtin_amdgcn_mfma_f32_16x16x32_bf16(onesv, pf[g][mi], lacc[mi], 0, 0, 0);
    }
    __builtin_amdgcn_s_setprio(0);

    asm volatile("s_waitcnt vmcnt(0)" ::: "memory");
    __syncthreads();
  };

  for (int j0 = 0; j0 < L; j0 += 128) {
    asm volatile("" : "+v"(ka[0]), "+v"(ka[1]),
                      "+v"(vo[0]), "+v"(vo[1]), "+v"(vo[2]), "+v"(vo[3]));
    body(0, ldsB1, true);
    body(16384, ldsB0, j0 + 128 < L);
  }

#pragma unroll
  for (int mi = 0; mi < 2; ++mi) {
    float inv = 1.0f / fmaxf(lacc[mi][0], 1e-30f);
    int token = q0 + w * 32 + mi * 16 + l16;
#pragma unroll
    for (int nd = 0; nd < 4; ++nd) {
      u16 h0 = f2bf(scrub(oT[nd][mi][0] * inv));
      u16 h1 = f2bf(scrub(oT[nd][mi][1] * inv));
      u16 h2 = f2bf(scrub(oT[nd][mi][2] * inv));
      u16 h3 = f2bf(scrub(oT[nd][mi][3] * inv));
      uint2 dw; dw.x = h0 | ((unsigned)h1 << 16); dw.y = h2 | ((unsigned)h3 << 16);
      *(uint2*)&O[((size_t)bh * L + token) * 64 + nd * 16 + quad * 4] = dw;
    }
  }
}

// ===========================================================================
extern "C" void kernel_launch(void* const* d_in, const int* in_sizes, int n_in,
                              void* d_out, int out_size, void* d_ws, size_t ws_size,
                              hipStream_t stream) {
  const float* q  = (const float*)d_in[0];
  const float* k  = (const float*)d_in[1];
  const float* v  = (const float*)d_in[2];
  const float* wq = (const float*)d_in[3];
  const float* wk = (const float*)d_in[4];
  const float* wv = (const float*)d_in[5];
  const float* wo = (const float*)d_in[6];
  float* out = (float*)d_out;

  const size_t NE = (size_t)4 * 16 * 2048 * 64;  // 8388608
  const size_t WN = (size_t)1024 * 1024;

  u16* wob = (u16*)d_ws;
  u16* Qh  = wob + WN;          // Q head-split (prescaled); attn overwrites it
  u16* Kh  = (u16*)d_out;       // K head-split in d_out (dead before final)
  u16* VTg = Kh + NE;           // V^T (B,H,DK,L)

  cvt1<<<dim3(1024), 256, 0, stream>>>(wo, wob);

  dim3 g1(8, 64, 3);
  proj3<<<g1, dim3(256), 0, stream>>>(q, k, v, wq, wk, wv, Qh, Kh, VTg);

  dim3 g2(16, 16, 4);
  attn3<<<g2, dim3(256), 0, stream>>>(Qh, Kh, VTg, Qh);

  dim3 g3(8, 64, 1);
  gemm_out<<<g3, dim3(256), 0, stream>>>(Qh, wob, out);
}